// Round 1
// baseline (481.617 us; speedup 1.0000x reference)
//
#include <hip/hip_runtime.h>

#define BB 16
#define HH 512
#define NH 32
#define LL 4096
#define TC 256
#define NCH 16            // LL/TC
#define BH (BB*HH)        // 8192

static_assert(LL / TC == NCH, "chunking");

typedef __attribute__((ext_vector_type(8))) short bf16x8;
typedef __attribute__((ext_vector_type(4))) float f32x4;

// RNE float->bf16 bits
static __device__ __forceinline__ unsigned short f2bf(float x) {
    unsigned int u = __builtin_bit_cast(unsigned int, x);
    u = (u + 0x7fffu + ((u >> 16) & 1u)) >> 16;
    return (unsigned short)u;
}

static __device__ __forceinline__ void gload_lds16(const void* g, void* l) {
#if __has_builtin(__builtin_amdgcn_global_load_lds)
    __builtin_amdgcn_global_load_lds(
        (const __attribute__((address_space(1))) unsigned int*)g,
        (__attribute__((address_space(3))) unsigned int*)l, 16, 0, 0);
#else
    *(uint4*)l = *(const uint4*)g;
#endif
}

// ---------------- K0: SSM parameters ----------------
__global__ void k0_params(const float* __restrict__ C,
                          const float* __restrict__ log_dt,
                          const float* __restrict__ lAr,
                          const float* __restrict__ Aim,
                          float* __restrict__ lamR, float* __restrict__ lamI,
                          float* __restrict__ c2R,  float* __restrict__ c2I,
                          float* __restrict__ ltR,  float* __restrict__ ltI)
{
    int tid = blockIdx.x * 256 + threadIdx.x;
    if (tid >= HH * NH) return;
    int h = tid >> 5;
    float dt = expf(log_dt[h]);
    float Ar = -expf(lAr[tid]);
    float Ai = Aim[tid];
    float xr = Ar * dt, xi = Ai * dt;
    float er = expf(xr);
    float lr = er * cosf(xi);
    float li = er * sinf(xi);
    lamR[tid] = lr; lamI[tid] = li;
    float wr = lr - 1.0f, wi = li;
    float inv = 1.0f / (Ar * Ar + Ai * Ai);
    float qr = (wr * Ar + wi * Ai) * inv;   // (Lam-1)/A
    float qi = (wi * Ar - wr * Ai) * inv;
    float cr = C[2 * tid], ci = C[2 * tid + 1];
    c2R[tid] =  2.0f * (cr * qr - ci * qi); // y += c2R*sr + c2I*si
    c2I[tid] = -2.0f * (cr * qi + ci * qr);
    float eT = expf((float)TC * xr);
    float aT = (float)TC * xi;
    ltR[tid] = eT * cosf(aT);               // Lambda^TC
    ltI[tid] = eT * sinf(aT);
}

// ---------------- Kw: pack W (row-permuted for GLU) + bias to bf16/f32 ----------------
__global__ void kw_pack(const float* __restrict__ W, const float* __restrict__ bias,
                        unsigned short* __restrict__ Wp, float* __restrict__ bp)
{
    int tid = blockIdx.x * 256 + threadIdx.x;      // 1024*64 = 65536
    int drow = tid >> 6;
    int kc = (tid & 63) * 8;
    int src = (drow & 1) ? (drow >> 1) + HH : (drow >> 1);
    const float4* s = (const float4*)(W + (size_t)src * HH + kc);
    float4 a = s[0], b4 = s[1];
    uint4 pack;
    pack.x = (unsigned)f2bf(a.x)  | ((unsigned)f2bf(a.y)  << 16);
    pack.y = (unsigned)f2bf(a.z)  | ((unsigned)f2bf(a.w)  << 16);
    pack.z = (unsigned)f2bf(b4.x) | ((unsigned)f2bf(b4.y) << 16);
    pack.w = (unsigned)f2bf(b4.z) | ((unsigned)f2bf(b4.w) << 16);
    *(uint4*)(Wp + (size_t)drow * HH + kc) = pack;
    if (tid < 2 * HH)
        bp[tid] = bias[(tid & 1) ? (tid >> 1) + HH : (tid >> 1)];
}

// ---------------- K1: per-chunk local end state E_c ----------------
#define S4D_STEP1(uq) { _Pragma("unroll") \
    for (int n = 0; n < NH; ++n) { \
        float nr = fmaf(lr[n], sr[n], fmaf(-li[n], si[n], (uq))); \
        float ni = fmaf(lr[n], si[n], li[n] * sr[n]); \
        sr[n] = nr; si[n] = ni; } }

__global__ __launch_bounds__(256, 2) void k1_local(
    const float* __restrict__ u,
    const float* __restrict__ lamR, const float* __restrict__ lamI,
    float* __restrict__ Ebuf)
{
    int tid = blockIdx.x * 256 + threadIdx.x;    // BH*NCH = 131072
    int c  = tid & (NCH - 1);
    int bh = tid >> 4;
    int h  = bh & (HH - 1);
    float lr[NH], li[NH], sr[NH], si[NH];
#pragma unroll
    for (int n = 0; n < NH; n += 4) {
        float4 a  = *(const float4*)(lamR + h * NH + n);
        float4 b4 = *(const float4*)(lamI + h * NH + n);
        lr[n] = a.x;  lr[n+1] = a.y;  lr[n+2] = a.z;  lr[n+3] = a.w;
        li[n] = b4.x; li[n+1] = b4.y; li[n+2] = b4.z; li[n+3] = b4.w;
        sr[n] = 0.f; sr[n+1] = 0.f; sr[n+2] = 0.f; sr[n+3] = 0.f;
        si[n] = 0.f; si[n+1] = 0.f; si[n+2] = 0.f; si[n+3] = 0.f;
    }
    const float4* up = (const float4*)(u + (size_t)bh * LL + c * TC);
    float4 uv = up[0];
    for (int t4 = 0; t4 < TC / 4; ++t4) {
        float4 un = (t4 + 1 < TC / 4) ? up[t4 + 1] : uv;
        S4D_STEP1(uv.x); S4D_STEP1(uv.y); S4D_STEP1(uv.z); S4D_STEP1(uv.w);
        uv = un;
    }
    float* e = Ebuf + ((size_t)bh * NCH + c) * (2 * NH);
#pragma unroll
    for (int n = 0; n < NH; n += 2) {
        float4 v; v.x = sr[n]; v.y = si[n]; v.z = sr[n+1]; v.w = si[n+1];
        *(float4*)(e + 2 * n) = v;
    }
}

// ---------------- K2: scan over chunks (in-place: Ebuf -> entry states) ----------------
__global__ void k2_scan(const float* __restrict__ ltR, const float* __restrict__ ltI,
                        float* __restrict__ Ebuf)
{
    int tid = blockIdx.x * 256 + threadIdx.x;    // BH*NH = 262144
    int n  = tid & (NH - 1);
    int bh = tid >> 5;
    int h  = bh & (HH - 1);
    float ar = ltR[h * NH + n], ai = ltI[h * NH + n];
    float srv = 0.f, siv = 0.f;
    float* base = Ebuf + (size_t)bh * NCH * (2 * NH) + 2 * n;
#pragma unroll
    for (int cc = 0; cc < NCH; ++cc) {
        float2 e = *(float2*)(base + cc * (2 * NH));
        *(float2*)(base + cc * (2 * NH)) = make_float2(srv, siv);
        float nsr = fmaf(ar, srv, fmaf(-ai, siv, e.x));
        float nsi = fmaf(ar, siv, fmaf(ai, srv, e.y));
        srv = nsr; siv = nsi;
    }
}

// ---------------- K3: full scan + D*u + GELU -> y bf16 in [b*l][h] layout ----------------
#define S4D_STEP3(uq, tt) { \
    float y0 = 0.f, y1 = 0.f, y2 = 0.f, y3 = 0.f; \
    _Pragma("unroll") \
    for (int n = 0; n < NH; ++n) { \
        float nr = fmaf(lr[n], sr[n], fmaf(-li[n], si[n], (uq))); \
        float ni = fmaf(lr[n], si[n], li[n] * sr[n]); \
        sr[n] = nr; si[n] = ni; \
        float& ya = ((n & 3) == 0) ? y0 : ((n & 3) == 1) ? y1 : ((n & 3) == 2) ? y2 : y3; \
        ya = fmaf(cr[n], nr, fmaf(ci[n], ni, ya)); } \
    float yt = (y0 + y1) + (y2 + y3); \
    float yo = fmaf(Dh, (uq), yt); \
    float ge = 0.5f * yo * (1.0f + erff(yo * 0.70710678118f)); \
    yp[(size_t)(tt) * HH] = f2bf(ge); }

__global__ __launch_bounds__(256, 2) void k3_out(
    const float* __restrict__ u,
    const float* __restrict__ lamR, const float* __restrict__ lamI,
    const float* __restrict__ c2R, const float* __restrict__ c2I,
    const float* __restrict__ Dv,
    const float* __restrict__ Ebuf,
    unsigned short* __restrict__ yb)
{
    int tid = blockIdx.x * 256 + threadIdx.x;    // 131072
    int c  = tid & (NCH - 1);
    int bh = tid >> 4;
    int h  = bh & (HH - 1);
    int b  = bh >> 9;
    float lr[NH], li[NH], cr[NH], ci[NH], sr[NH], si[NH];
#pragma unroll
    for (int n = 0; n < NH; n += 4) {
        float4 a  = *(const float4*)(lamR + h * NH + n);
        float4 b4 = *(const float4*)(lamI + h * NH + n);
        float4 p  = *(const float4*)(c2R  + h * NH + n);
        float4 q  = *(const float4*)(c2I  + h * NH + n);
        lr[n] = a.x;  lr[n+1] = a.y;  lr[n+2] = a.z;  lr[n+3] = a.w;
        li[n] = b4.x; li[n+1] = b4.y; li[n+2] = b4.z; li[n+3] = b4.w;
        cr[n] = p.x;  cr[n+1] = p.y;  cr[n+2] = p.z;  cr[n+3] = p.w;
        ci[n] = q.x;  ci[n+1] = q.y;  ci[n+2] = q.z;  ci[n+3] = q.w;
    }
    const float* e = Ebuf + ((size_t)bh * NCH + c) * (2 * NH);
#pragma unroll
    for (int n = 0; n < NH; n += 2) {
        float4 v = *(const float4*)(e + 2 * n);
        sr[n] = v.x; si[n] = v.y; sr[n+1] = v.z; si[n+1] = v.w;
    }
    float Dh = Dv[h];
    const float4* up = (const float4*)(u + (size_t)bh * LL + c * TC);
    unsigned short* yp = yb + ((size_t)b * LL + (size_t)c * TC) * HH + h;
    float4 uv = up[0];
    for (int t4 = 0; t4 < TC / 4; ++t4) {
        float4 un = (t4 + 1 < TC / 4) ? up[t4 + 1] : uv;
        S4D_STEP3(uv.x, 4 * t4 + 0);
        S4D_STEP3(uv.y, 4 * t4 + 1);
        S4D_STEP3(uv.z, 4 * t4 + 2);
        S4D_STEP3(uv.w, 4 * t4 + 3);
        uv = un;
    }
}

// ---------------- K4: GEMM z = Wp*y + bp, fused GLU (m97 structure) ----------------
#define BM 128
#define BN 128
#define BKK 32

__global__ __launch_bounds__(256, 2) void k4_gemm(
    const unsigned short* __restrict__ Wp, const float* __restrict__ bp,
    const unsigned short* __restrict__ yb, float* __restrict__ out)
{
    __shared__ unsigned short As[BM * BKK];   // [row][k]
    __shared__ unsigned short Bs[BN * BKK];   // [n][k]  (B^T layout)
    int tid  = threadIdx.x;
    int bidx = blockIdx.x;
    int mtile = bidx & 7, ntile = bidx >> 3;  // mtile fastest: 8 blocks share B panel
    int mbase = mtile * BM, nbase = ntile * BN;
    int lane = tid & 63;
    int wv = tid >> 6;
    int wr = wv >> 1, wc = wv & 1;
    int lrow = lane & 15;
    int lk = (lane >> 4) * 8;

    f32x4 acc[4][4];
#pragma unroll
    for (int m = 0; m < 4; ++m)
#pragma unroll
        for (int n = 0; n < 4; ++n) { f32x4 z = {0.f, 0.f, 0.f, 0.f}; acc[m][n] = z; }

    for (int kk = 0; kk < HH; kk += BKK) {
#pragma unroll
        for (int p = 0; p < 2; ++p) {
            int chunk = p * 256 + tid;
            int row = chunk >> 2;
            int kc  = (chunk & 3) * 8;
            gload_lds16(Wp + (size_t)(mbase + row) * HH + kk + kc, &As[chunk * 8]);
            gload_lds16(yb + (size_t)(nbase + row) * HH + kk + kc, &Bs[chunk * 8]);
        }
        __syncthreads();
        bf16x8 af[4], bfr[4];
#pragma unroll
        for (int m = 0; m < 4; ++m)
            af[m] = *(const bf16x8*)&As[(wr * 64 + m * 16 + lrow) * BKK + lk];
#pragma unroll
        for (int nf = 0; nf < 4; ++nf)
            bfr[nf] = *(const bf16x8*)&Bs[(wc * 64 + nf * 16 + lrow) * BKK + lk];
#pragma unroll
        for (int m = 0; m < 4; ++m)
#pragma unroll
            for (int nf = 0; nf < 4; ++nf)
                acc[m][nf] = __builtin_amdgcn_mfma_f32_16x16x32_bf16(af[m], bfr[nf], acc[m][nf], 0, 0, 0);
        __syncthreads();
    }
    // epilogue: bias + GLU (rows interleaved a,g)
#pragma unroll
    for (int m = 0; m < 4; ++m) {
        int go = mbase + wr * 64 + m * 16 + ((lane >> 4) * 4);   // even
        float4 bv = *(const float4*)(bp + go);
#pragma unroll
        for (int nf = 0; nf < 4; ++nf) {
            int col  = nbase + wc * 64 + nf * 16 + lrow;
            int bcol = col >> 12;
            int lcol = col & (LL - 1);
            f32x4 v = acc[m][nf];
            float a0 = v[0] + bv.x, g0 = v[1] + bv.y;
            float a1 = v[2] + bv.z, g1 = v[3] + bv.w;
            float o0 = a0 / (1.0f + __expf(-g0));
            float o1 = a1 / (1.0f + __expf(-g1));
            size_t ob = ((size_t)bcol * HH + (size_t)(go >> 1)) * LL + lcol;
            out[ob] = o0;
            out[ob + LL] = o1;
        }
    }
}

extern "C" void kernel_launch(void* const* d_in, const int* in_sizes, int n_in,
                              void* d_out, int out_size, void* d_ws, size_t ws_size,
                              hipStream_t stream) {
    const float* u    = (const float*)d_in[0];
    const float* C    = (const float*)d_in[1];
    const float* ldt  = (const float*)d_in[2];
    const float* lar  = (const float*)d_in[3];
    const float* aim  = (const float*)d_in[4];
    const float* Dv   = (const float*)d_in[5];
    const float* W    = (const float*)d_in[6];
    const float* bias = (const float*)d_in[7];
    float* out = (float*)d_out;

    // ws layout (total ~102.1 MB)
    char* w = (char*)d_ws;
    float* lamR = (float*)w; w += (size_t)HH * NH * 4;
    float* lamI = (float*)w; w += (size_t)HH * NH * 4;
    float* c2R  = (float*)w; w += (size_t)HH * NH * 4;
    float* c2I  = (float*)w; w += (size_t)HH * NH * 4;
    float* ltR  = (float*)w; w += (size_t)HH * NH * 4;
    float* ltI  = (float*)w; w += (size_t)HH * NH * 4;
    float* bp   = (float*)w; w += (size_t)2 * HH * 4;
    unsigned short* Wp = (unsigned short*)w; w += (size_t)2 * HH * HH * 2;
    float* Ebuf = (float*)w; w += (size_t)BH * NCH * 2 * NH * 4;
    unsigned short* yb = (unsigned short*)w; w += (size_t)BB * LL * HH * 2;

    k0_params<<<dim3(64),  dim3(256), 0, stream>>>(C, ldt, lar, aim, lamR, lamI, c2R, c2I, ltR, ltI);
    kw_pack  <<<dim3(256), dim3(256), 0, stream>>>(W, bias, Wp, bp);
    k1_local <<<dim3(512), dim3(256), 0, stream>>>(u, lamR, lamI, Ebuf);
    k2_scan  <<<dim3(1024),dim3(256), 0, stream>>>(ltR, ltI, Ebuf);
    k3_out   <<<dim3(512), dim3(256), 0, stream>>>(u, lamR, lamI, c2R, c2I, Dv, Ebuf, yb);
    k4_gemm  <<<dim3(4096),dim3(256), 0, stream>>>(Wp, bp, yb, out);
}